// Round 6
// baseline (127.336 us; speedup 1.0000x reference)
//
#include <hip/hip_runtime.h>
#include <stdint.h>

typedef __attribute__((ext_vector_type(8))) __bf16 bf16x8;
typedef __attribute__((ext_vector_type(4))) float f32x4;
typedef unsigned short u16;

__device__ __forceinline__ u16 f2bf(float f) {
  unsigned u = __builtin_bit_cast(unsigned, f);
  unsigned r = 0x7FFFu + ((u >> 16) & 1u);
  return (u16)((u + r) >> 16);
}

__device__ __forceinline__ void gload16(const void* g, void* l) {
  __builtin_amdgcn_global_load_lds(
      (__attribute__((address_space(1))) void*)(g),
      (__attribute__((address_space(3))) void*)(l),
      16, 0, 0);
}

// ---- deg / rsqrt -----------------------------------------------------------
__global__ void row_deg_k(const float* __restrict__ adj, float* __restrict__ dis, int N) {
  int row = blockIdx.x;
  const float4* a = (const float4*)(adj + (size_t)row * N);
  float s = 0.f;
  for (int j = threadIdx.x; j < N / 4; j += 256) {
    float4 v = a[j];
    s += v.x + v.y + v.z + v.w;
  }
#pragma unroll
  for (int off = 32; off > 0; off >>= 1) s += __shfl_down(s, off, 64);
  __shared__ float wsum[4];
  if ((threadIdx.x & 63) == 0) wsum[threadIdx.x >> 6] = s;
  __syncthreads();
  if (threadIdx.x == 0) {
    float t = wsum[0] + wsum[1] + wsum[2] + wsum[3];
    dis[row] = (t > 0.f) ? (1.0f / sqrtf(t)) : 0.f;
  }
}

// ---- fp32 -> bf16 vectorized ----------------------------------------------
__global__ void conv_bf16_k(const float* __restrict__ in, u16* __restrict__ o, int n4) {
  int i = blockIdx.x * 256 + threadIdx.x;
  if (i >= n4) return;
  float4 v = ((const float4*)in)[i];
  ushort4 u;
  u.x = f2bf(v.x); u.y = f2bf(v.y); u.z = f2bf(v.z); u.w = f2bf(v.w);
  ((ushort4*)o)[i] = u;
}

// ---- W [512,512] -> W^T bf16 ----------------------------------------------
__global__ void conv_wt_k(const float* __restrict__ w, u16* __restrict__ wt) {
  int idx = blockIdx.x * 256 + threadIdx.x;  // 262144 total
  int i = idx >> 9, o = idx & 511;
  wt[o * 512 + i] = f2bf(w[idx]);
}

// ---- norm_adj bf16 ---------------------------------------------------------
__global__ void make_nadj_k(const float* __restrict__ adj, const float* __restrict__ dis,
                            u16* __restrict__ o, int N) {
  int idx = blockIdx.x * 256 + threadIdx.x;  // per float4, N*N/4 total
  int i = idx >> 9;                          // N/4 = 512 float4 per row
  int j4 = (idx & 511) * 4;
  float di = dis[i];
  float4 a = ((const float4*)adj)[idx];
  ushort4 u;
  u.x = f2bf(a.x * di * dis[j4 + 0]);
  u.y = f2bf(a.y * di * dis[j4 + 1]);
  u.z = f2bf(a.z * di * dis[j4 + 2]);
  u.w = f2bf(a.w * di * dis[j4 + 3]);
  ((ushort4*)o)[idx] = u;
}

// ---- 256x256 bf16 GEMM, m201-faithful 4-phase/K-tile schedule --------------
// C = A[M,K] * Bt[N,K]^T. 512 threads (8 waves, 2Mx4N), BK=64, 128 KiB LDS
// double-buffered, zero-conflict XOR swizzle (elem ^= (row&7)<<3, both sides).
// Per phase: {ds_reads + stage 1 half-tile (2 gloads) -> barrier -> lgkmcnt(0)
// -> setprio(1) -> 16 MFMA -> setprio(0) -> [counted vmcnt] -> barrier}.
// Staging runs 2 tiles ahead; vmcnt(12) at P2, vmcnt(6) at P4, never 0.
// Units: A-half h = rows {h*64..}+{h*64+128..}; B-half h = rows h*128..+127.
// Slot-safety: every staged slot's last readers drained at a previous
// lgkmcnt(0)-before-MFMA; staged data only read after a vmcnt->barrier pair.
// EPI=0: bf16 C^T write; EPI=1: f32 C + bias.
template <int EPI>
__launch_bounds__(512, 2)
__global__ void gemm256_k(const u16* __restrict__ A, int lda,
                          const u16* __restrict__ Bt, int ldb,
                          void* __restrict__ Cv, int ldc,
                          const float* __restrict__ bias, int K,
                          int nMT, int nNT, size_t zBt, size_t zC) {
  __shared__ __align__(16) u16 lds[65536];  // A:[2][256][64] @0, B:[2][256][64] @32768

  const int tid = threadIdx.x;
  const int lane = tid & 63;
  const int wid = tid >> 6;
  const int wr = wid >> 2;   // 0..1  (M)
  const int wc = wid & 3;    // 0..3  (N)

  // bijective XCD swizzle (gridDim.x == 256, divisible by 8)
  const int flat = blockIdx.x;
  const int wg = (flat & 7) * ((int)gridDim.x >> 3) + (flat >> 3);
  const int m_t = wg % nMT;
  const int rest = wg / nMT;
  const int n_t = rest % nNT;
  const int b = rest / nNT;
  const int rowBase = m_t * 256;
  const int colBase = n_t * 256;
  const u16* Bb = Bt + (size_t)b * zBt;

  // staging: per-thread row lr, linear LDS col kkl, pre-swizzled global col
  const int lr = tid >> 3;            // 0..63
  const int kkl = (tid & 7) * 8;      // 0..56
  const int kswz = kkl ^ ((lr & 7) << 3);
  const u16* gA = A + (size_t)(rowBase + lr) * lda + kswz;
  const u16* gB = Bb + (size_t)(colBase + lr) * ldb + kswz;
  u16* lA = lds + lr * 64 + kkl;
  u16* lB = lds + 32768 + lr * 64 + kkl;

  // fragment reads: row = base + (lane&15); granule XOR on row bits 0-2
  const int fr = lane & 15;
  const int rswz = (lane & 7) << 3;
  const int kp0 = ((lane >> 4) * 8) ^ rswz;
  const int kp1 = (32 | ((lane >> 4) * 8)) ^ rswz;
  const u16* fA = lds + (wr * 128 + fr) * 64;
  const u16* fB = lds + 32768 + (wc * 64 + fr) * 64;

  f32x4 acc[8][4] = {};
  bf16x8 a0[4], a1[4], b0[4], b1[4];

  const int NT = K >> 6;

#define STAGE_A(d, h, t)                                                             \
  do {                                                                               \
    gload16(gA + (size_t)((h) * 64) * lda + (size_t)(t) * 64,                        \
            lA + (d) * 16384 + ((h) * 64) * 64);                                     \
    gload16(gA + (size_t)((h) * 64 + 128) * lda + (size_t)(t) * 64,                  \
            lA + (d) * 16384 + ((h) * 64 + 128) * 64);                               \
  } while (0)

#define STAGE_B(d, h, t)                                                             \
  do {                                                                               \
    gload16(gB + (size_t)((h) * 128) * ldb + (size_t)(t) * 64,                       \
            lB + (d) * 16384 + ((h) * 128) * 64);                                    \
    gload16(gB + (size_t)((h) * 128 + 64) * ldb + (size_t)(t) * 64,                  \
            lB + (d) * 16384 + ((h) * 128 + 64) * 64);                               \
  } while (0)

#define RD_A8(mh, c)                                                                 \
  _Pragma("unroll") for (int m = 0; m < 4; ++m) {                                    \
    a0[m] = *(const bf16x8*)(fA + (c) * 16384 + (mh) * 4096 + m * 1024 + kp0);       \
    a1[m] = *(const bf16x8*)(fA + (c) * 16384 + (mh) * 4096 + m * 1024 + kp1);       \
  }

#define RD_B4(nlo, c)                                                                \
  _Pragma("unroll") for (int n = 0; n < 2; ++n) {                                    \
    b0[(nlo) + n] = *(const bf16x8*)(fB + (c) * 16384 + ((nlo) + n) * 1024 + kp0);   \
    b1[(nlo) + n] = *(const bf16x8*)(fB + (c) * 16384 + ((nlo) + n) * 1024 + kp1);   \
  }

#define PRE()                                                                        \
  __builtin_amdgcn_sched_barrier(0);                                                 \
  __builtin_amdgcn_s_barrier();                                                      \
  asm volatile("s_waitcnt lgkmcnt(0)" ::: "memory");                                 \
  __builtin_amdgcn_sched_barrier(0);                                                 \
  __builtin_amdgcn_s_setprio(1)

#define POST()                                                                       \
  __builtin_amdgcn_s_setprio(0);                                                     \
  __builtin_amdgcn_sched_barrier(0)

#define MFMA_Q(mh, nlo)                                                              \
  _Pragma("unroll") for (int m = 0; m < 4; ++m) {                                    \
    _Pragma("unroll") for (int n = 0; n < 2; ++n) {                                  \
      acc[(mh) * 4 + m][(nlo) + n] = __builtin_amdgcn_mfma_f32_16x16x32_bf16(        \
          a0[m], b0[(nlo) + n], acc[(mh) * 4 + m][(nlo) + n], 0, 0, 0);              \
      acc[(mh) * 4 + m][(nlo) + n] = __builtin_amdgcn_mfma_f32_16x16x32_bf16(        \
          a1[m], b1[(nlo) + n], acc[(mh) * 4 + m][(nlo) + n], 0, 0, 0);              \
    }                                                                                \
  }

  // prologue: 7 units in deadline order; vmcnt(6) -> tile0 (incl. A1) landed
  {
    const int t1 = (NT > 1) ? 1 : 0;
    STAGE_A(0, 0, 0);   // A0(0)
    STAGE_B(0, 0, 0);   // B0(0)
    STAGE_B(0, 1, 0);   // B1(0)
    STAGE_A(0, 1, 0);   // A1(0)
    STAGE_A(1, 0, t1);  // A0(1)
    STAGE_B(1, 0, t1);  // B0(1)
    STAGE_A(1, 1, t1);  // A1(1)
    asm volatile("s_waitcnt vmcnt(6)" ::: "memory");
    __builtin_amdgcn_s_barrier();
  }

  for (int t = 0; t < NT; ++t) {
    const int c = t & 1;
    const int cn = c ^ 1;
    const int tB1 = (t + 1 < NT) ? t + 1 : NT - 1;  // tail clamps: staged, never read
    const int t2 = (t + 2 < NT) ? t + 2 : NT - 1;

    // P1: reads A(mh0,both kh)+B(n01,both kh); stage B1(t+1)->buf cn
    RD_A8(0, c);
    RD_B4(0, c);
    STAGE_B(cn, 1, tB1);
    asm volatile("s_waitcnt lgkmcnt(8)" ::: "memory");  // early drain of 12-read phase
    PRE();
    MFMA_Q(0, 0);
    POST();
    __builtin_amdgcn_s_barrier();

    // P2: reads B(n23,both kh); stage A0(t+2)->buf c (A-half0 dead after P1)
    RD_B4(2, c);
    STAGE_A(c, 0, t2);
    PRE();
    MFMA_Q(0, 2);
    POST();
    asm volatile("s_waitcnt vmcnt(12)" ::: "memory");  // gates A1(t) for P3 reads
    __builtin_amdgcn_s_barrier();

    // P3: reads A(mh1,both kh); stage B0(t+2)->buf c (B reads done after P2)
    RD_A8(1, c);
    STAGE_B(c, 0, t2);
    PRE();
    MFMA_Q(1, 2);
    POST();
    __builtin_amdgcn_s_barrier();

    // P4: no reads; stage A1(t+2)->buf c (A-half1 dead after P3)
    STAGE_A(c, 1, t2);
    PRE();
    MFMA_Q(1, 0);
    POST();
    asm volatile("s_waitcnt vmcnt(6)" ::: "memory");  // gates A0/B0/B1(t+1) for next P1
    __builtin_amdgcn_s_barrier();
  }
  asm volatile("s_waitcnt vmcnt(0)" ::: "memory");  // drain clamped tail stages

  if (EPI == 0) {
    u16* C = (u16*)Cv;
#pragma unroll
    for (int am = 0; am < 8; ++am) {
      const int r = rowBase + wr * 128 + (am >> 2) * 64 + (am & 3) * 16 + (lane >> 4) * 4;
#pragma unroll
      for (int n = 0; n < 4; ++n) {
        const int cc = colBase + wc * 64 + n * 16 + (lane & 15);
        ushort4 v;
        v.x = f2bf(acc[am][n][0]);
        v.y = f2bf(acc[am][n][1]);
        v.z = f2bf(acc[am][n][2]);
        v.w = f2bf(acc[am][n][3]);
        *reinterpret_cast<ushort4*>(&C[(size_t)cc * ldc + r]) = v;
      }
    }
  } else {
    float* C = (float*)Cv + (size_t)b * zC;
#pragma unroll
    for (int n = 0; n < 4; ++n) {
      const int cc = colBase + wc * 64 + n * 16 + (lane & 15);
      const float bv = bias[cc];
#pragma unroll
      for (int am = 0; am < 8; ++am) {
        const int r = rowBase + wr * 128 + (am >> 2) * 64 + (am & 3) * 16 + (lane >> 4) * 4;
#pragma unroll
        for (int j = 0; j < 4; ++j)
          C[(size_t)(r + j) * ldc + cc] = acc[am][n][j] + bv;
      }
    }
  }
#undef STAGE_A
#undef STAGE_B
#undef RD_A8
#undef RD_B4
#undef PRE
#undef POST
#undef MFMA_Q
}

extern "C" void kernel_launch(void* const* d_in, const int* in_sizes, int n_in,
                              void* d_out, int out_size, void* d_ws, size_t ws_size,
                              hipStream_t stream) {
  const int B = 16, N = 2048, FIN = 512, FOUT = 512;
  const float* x    = (const float*)d_in[0];
  const float* adj  = (const float*)d_in[1];
  const float* w    = (const float*)d_in[2];
  const float* bias = (const float*)d_in[3];
  float* out = (float*)d_out;
  char* ws = (char*)d_ws;

  float* dis = (float*)ws;                       // 8 KB
  u16* wt    = (u16*)(ws + 8192);                // 512 KB  W^T [FOUT][FIN]
  u16* nadj  = (u16*)(ws + 532480);              // 8 MB    [N][N]
  u16* xb    = (u16*)(ws + 8921088);             // 32 MB   [B*N][FIN]
  u16* st    = (u16*)(ws + 42475520);            // 32 MB   support^T [FOUT][B*N]

  row_deg_k<<<N, 256, 0, stream>>>(adj, dis, N);
  conv_bf16_k<<<(B * N * FIN / 4 + 255) / 256, 256, 0, stream>>>(x, xb, B * N * FIN / 4);
  conv_wt_k<<<(FIN * FOUT) / 256, 256, 0, stream>>>(w, wt);
  make_nadj_k<<<(N * N / 4) / 256, 256, 0, stream>>>(adj, dis, nadj, N);

  // GEMM1: support^T = (xb @ wt^T)^T : A=xb [32768,512], Bt=wt [512,512]
  // grid = 128*2*1 = 256 blocks
  gemm256_k<0><<<dim3(256), 512, 0, stream>>>(
      xb, FIN, wt, FIN, st, B * N, nullptr, FIN, 128, 2, 0, 0);

  // GEMM2: out[b] = nadj @ support[b] + bias : A=nadj [2048,2048],
  // Bt = st + b*2048 (ldb=32768, K=N), C = out + b*N*FOUT
  // grid = 8*2*16 = 256 blocks
  gemm256_k<1><<<dim3(256), 512, 0, stream>>>(
      nadj, N, st, B * N, out, FOUT, bias, N, 8, 2,
      (size_t)N, (size_t)N * FOUT);
}

// Round 7
// 124.614 us; speedup vs baseline: 1.0218x; 1.0218x over previous
//
#include <hip/hip_runtime.h>
#include <stdint.h>

typedef __attribute__((ext_vector_type(8))) __bf16 bf16x8;
typedef __attribute__((ext_vector_type(4))) float f32x4;
typedef unsigned short u16;

__device__ __forceinline__ u16 f2bf(float f) {
  unsigned u = __builtin_bit_cast(unsigned, f);
  unsigned r = 0x7FFFu + ((u >> 16) & 1u);
  return (u16)((u + r) >> 16);
}

__device__ __forceinline__ void gload16(const void* g, void* l) {
  __builtin_amdgcn_global_load_lds(
      (__attribute__((address_space(1))) void*)(g),
      (__attribute__((address_space(3))) void*)(l),
      16, 0, 0);
}

// ---- deg / rsqrt -----------------------------------------------------------
__global__ void row_deg_k(const float* __restrict__ adj, float* __restrict__ dis, int N) {
  int row = blockIdx.x;
  const float4* a = (const float4*)(adj + (size_t)row * N);
  float s = 0.f;
  for (int j = threadIdx.x; j < N / 4; j += 256) {
    float4 v = a[j];
    s += v.x + v.y + v.z + v.w;
  }
#pragma unroll
  for (int off = 32; off > 0; off >>= 1) s += __shfl_down(s, off, 64);
  __shared__ float wsum[4];
  if ((threadIdx.x & 63) == 0) wsum[threadIdx.x >> 6] = s;
  __syncthreads();
  if (threadIdx.x == 0) {
    float t = wsum[0] + wsum[1] + wsum[2] + wsum[3];
    dis[row] = (t > 0.f) ? (1.0f / sqrtf(t)) : 0.f;
  }
}

// ---- fp32 -> bf16 vectorized ----------------------------------------------
__global__ void conv_bf16_k(const float* __restrict__ in, u16* __restrict__ o, int n4) {
  int i = blockIdx.x * 256 + threadIdx.x;
  if (i >= n4) return;
  float4 v = ((const float4*)in)[i];
  ushort4 u;
  u.x = f2bf(v.x); u.y = f2bf(v.y); u.z = f2bf(v.z); u.w = f2bf(v.w);
  ((ushort4*)o)[i] = u;
}

// ---- W [512,512] -> W^T bf16 ----------------------------------------------
__global__ void conv_wt_k(const float* __restrict__ w, u16* __restrict__ wt) {
  int idx = blockIdx.x * 256 + threadIdx.x;  // 262144 total
  int i = idx >> 9, o = idx & 511;
  wt[o * 512 + i] = f2bf(w[idx]);
}

// ---- norm_adj bf16 ---------------------------------------------------------
__global__ void make_nadj_k(const float* __restrict__ adj, const float* __restrict__ dis,
                            u16* __restrict__ o, int N) {
  int idx = blockIdx.x * 256 + threadIdx.x;  // per float4, N*N/4 total
  int i = idx >> 9;                          // N/4 = 512 float4 per row
  int j4 = (idx & 511) * 4;
  float di = dis[i];
  float4 a = ((const float4*)adj)[idx];
  ushort4 u;
  u.x = f2bf(a.x * di * dis[j4 + 0]);
  u.y = f2bf(a.y * di * dis[j4 + 1]);
  u.z = f2bf(a.z * di * dis[j4 + 2]);
  u.w = f2bf(a.w * di * dis[j4 + 3]);
  ((ushort4*)o)[idx] = u;
}

// ---- 256x256 bf16 GEMM, 1 syncthreads/K-tile, compiler-scheduled body ------
// C = A[M,K] * Bt[N,K]^T. 512 threads (8 waves, 2Mx4N), BK=64, 128 KiB LDS
// double-buffered, zero-conflict XOR swizzle (elem ^= (row&7)<<3, both sides).
// Per tile: issue-early STAGE of t+1 (8 global_load_lds, drained by the
// NEXT __syncthreads ~2500cyc later), then UNPINNED 24 ds_read_b128 + 64 MFMA
// (kh-outer): the compiler emits counted lgkmcnt interleave (m97 pattern).
// No sched_barrier pins except one keeping the stage at the top.
// EPI=0: bf16 C^T write; EPI=1: f32 C + bias.
template <int EPI>
__launch_bounds__(512, 2)
__global__ void gemm256_k(const u16* __restrict__ A, int lda,
                          const u16* __restrict__ Bt, int ldb,
                          void* __restrict__ Cv, int ldc,
                          const float* __restrict__ bias, int K,
                          int nMT, int nNT, size_t zBt, size_t zC) {
  __shared__ __align__(16) u16 lds[65536];  // A:[2][256][64] @0, B:[2][256][64] @32768

  const int tid = threadIdx.x;
  const int lane = tid & 63;
  const int wid = tid >> 6;
  const int wr = wid >> 2;   // 0..1  (M)
  const int wc = wid & 3;    // 0..3  (N)

  // bijective XCD swizzle (gridDim.x == 256, divisible by 8)
  const int flat = blockIdx.x;
  const int wg = (flat & 7) * ((int)gridDim.x >> 3) + (flat >> 3);
  const int m_t = wg % nMT;
  const int rest = wg / nMT;
  const int n_t = rest % nNT;
  const int b = rest / nNT;
  const int rowBase = m_t * 256;
  const int colBase = n_t * 256;
  const u16* Bb = Bt + (size_t)b * zBt;

  // staging: per-thread row lr, linear LDS col kkl, pre-swizzled global col
  const int lr = tid >> 3;            // 0..63
  const int kkl = (tid & 7) * 8;      // 0..56
  const int kswz = kkl ^ ((lr & 7) << 3);
  const u16* gA = A + (size_t)(rowBase + lr) * lda + kswz;
  const u16* gB = Bb + (size_t)(colBase + lr) * ldb + kswz;
  u16* lA = lds + lr * 64 + kkl;
  u16* lB = lds + 32768 + lr * 64 + kkl;

  // fragment reads: row = base + (lane&15); granule XOR on row bits 0-2
  const int fr = lane & 15;
  const int rswz = (lane & 7) << 3;
  const int kp0 = ((lane >> 4) * 8) ^ rswz;
  const int kp1 = (32 | ((lane >> 4) * 8)) ^ rswz;
  const u16* fA = lds + (wr * 128 + fr) * 64;
  const u16* fB = lds + 32768 + (wc * 64 + fr) * 64;

  f32x4 acc[8][4] = {};

  const int NT = K >> 6;

#define STAGE_ALL(d, t)                                                              \
  _Pragma("unroll") for (int r4 = 0; r4 < 4; ++r4) {                                 \
    gload16(gA + (size_t)(r4 * 64) * lda + (size_t)(t) * 64,                         \
            lA + (d) * 16384 + r4 * 4096);                                           \
    gload16(gB + (size_t)(r4 * 64) * ldb + (size_t)(t) * 64,                         \
            lB + (d) * 16384 + r4 * 4096);                                           \
  }

  // prologue: stage tile0 into buf0 (syncthreads drains vmcnt+lgkm, barriers)
  STAGE_ALL(0, 0);
  __syncthreads();

  for (int t = 0; t < NT; ++t) {
    const int c = t & 1;
    const int cn = c ^ 1;
    const int tn = (t + 1 < NT) ? t + 1 : NT - 1;  // tail clamp: staged, never read

    STAGE_ALL(cn, tn);                    // issue-early; drains at tile-end sync
    __builtin_amdgcn_sched_barrier(0);    // keep stage at top; body unpinned below

    bf16x8 a0[8], a1[8], b0[4], b1[4];
#pragma unroll
    for (int m = 0; m < 8; ++m) {
      a0[m] = *(const bf16x8*)(fA + c * 16384 + m * 1024 + kp0);
      a1[m] = *(const bf16x8*)(fA + c * 16384 + m * 1024 + kp1);
    }
#pragma unroll
    for (int n = 0; n < 4; ++n) {
      b0[n] = *(const bf16x8*)(fB + c * 16384 + n * 1024 + kp0);
      b1[n] = *(const bf16x8*)(fB + c * 16384 + n * 1024 + kp1);
    }
#pragma unroll
    for (int m = 0; m < 8; ++m)
#pragma unroll
      for (int n = 0; n < 4; ++n)
        acc[m][n] = __builtin_amdgcn_mfma_f32_16x16x32_bf16(a0[m], b0[n], acc[m][n], 0, 0, 0);
#pragma unroll
    for (int m = 0; m < 8; ++m)
#pragma unroll
      for (int n = 0; n < 4; ++n)
        acc[m][n] = __builtin_amdgcn_mfma_f32_16x16x32_bf16(a1[m], b1[n], acc[m][n], 0, 0, 0);

    __syncthreads();                      // drains vm (stage) + lgkm (reads), barrier
  }

  if (EPI == 0) {
    u16* C = (u16*)Cv;
#pragma unroll
    for (int m = 0; m < 8; ++m) {
      const int r = rowBase + wr * 128 + m * 16 + (lane >> 4) * 4;
#pragma unroll
      for (int n = 0; n < 4; ++n) {
        const int cc = colBase + wc * 64 + n * 16 + (lane & 15);
        ushort4 v;
        v.x = f2bf(acc[m][n][0]);
        v.y = f2bf(acc[m][n][1]);
        v.z = f2bf(acc[m][n][2]);
        v.w = f2bf(acc[m][n][3]);
        *reinterpret_cast<ushort4*>(&C[(size_t)cc * ldc + r]) = v;
      }
    }
  } else {
    float* C = (float*)Cv + (size_t)b * zC;
#pragma unroll
    for (int n = 0; n < 4; ++n) {
      const int cc = colBase + wc * 64 + n * 16 + (lane & 15);
      const float bv = bias[cc];
#pragma unroll
      for (int m = 0; m < 8; ++m) {
        const int r = rowBase + wr * 128 + m * 16 + (lane >> 4) * 4;
#pragma unroll
        for (int j = 0; j < 4; ++j)
          C[(size_t)(r + j) * ldc + cc] = acc[m][n][j] + bv;
      }
    }
  }
#undef STAGE_ALL
}

extern "C" void kernel_launch(void* const* d_in, const int* in_sizes, int n_in,
                              void* d_out, int out_size, void* d_ws, size_t ws_size,
                              hipStream_t stream) {
  const int B = 16, N = 2048, FIN = 512, FOUT = 512;
  const float* x    = (const float*)d_in[0];
  const float* adj  = (const float*)d_in[1];
  const float* w    = (const float*)d_in[2];
  const float* bias = (const float*)d_in[3];
  float* out = (float*)d_out;
  char* ws = (char*)d_ws;

  float* dis = (float*)ws;                       // 8 KB
  u16* wt    = (u16*)(ws + 8192);                // 512 KB  W^T [FOUT][FIN]
  u16* nadj  = (u16*)(ws + 532480);              // 8 MB    [N][N]
  u16* xb    = (u16*)(ws + 8921088);             // 32 MB   [B*N][FIN]
  u16* st    = (u16*)(ws + 42475520);            // 32 MB   support^T [FOUT][B*N]

  row_deg_k<<<N, 256, 0, stream>>>(adj, dis, N);
  conv_bf16_k<<<(B * N * FIN / 4 + 255) / 256, 256, 0, stream>>>(x, xb, B * N * FIN / 4);
  conv_wt_k<<<(FIN * FOUT) / 256, 256, 0, stream>>>(w, wt);
  make_nadj_k<<<(N * N / 4) / 256, 256, 0, stream>>>(adj, dis, nadj, N);

  // GEMM1: support^T = (xb @ wt^T)^T : A=xb [32768,512], Bt=wt [512,512]
  // grid = 128*2*1 = 256 blocks
  gemm256_k<0><<<dim3(256), 512, 0, stream>>>(
      xb, FIN, wt, FIN, st, B * N, nullptr, FIN, 128, 2, 0, 0);

  // GEMM2: out[b] = nadj @ support[b] + bias : A=nadj [2048,2048],
  // Bt = st + b*2048 (ldb=32768, K=N), C = out + b*N*FOUT
  // grid = 8*2*16 = 256 blocks
  gemm256_k<1><<<dim3(256), 512, 0, stream>>>(
      nadj, N, st, B * N, out, FOUT, bias, N, 8, 2,
      (size_t)N, (size_t)N * FOUT);
}

// Round 8
// 124.474 us; speedup vs baseline: 1.0230x; 1.0011x over previous
//
#include <hip/hip_runtime.h>
#include <stdint.h>

typedef __attribute__((ext_vector_type(8))) __bf16 bf16x8;
typedef __attribute__((ext_vector_type(4))) float f32x4;
typedef unsigned short u16;

__device__ __forceinline__ u16 f2bf(float f) {
  unsigned u = __builtin_bit_cast(unsigned, f);
  unsigned r = 0x7FFFu + ((u >> 16) & 1u);
  return (u16)((u + r) >> 16);
}

__device__ __forceinline__ void gload16(const void* g, void* l) {
  __builtin_amdgcn_global_load_lds(
      (__attribute__((address_space(1))) void*)(g),
      (__attribute__((address_space(3))) void*)(l),
      16, 0, 0);
}

// ---- deg / rsqrt -----------------------------------------------------------
__global__ void row_deg_k(const float* __restrict__ adj, float* __restrict__ dis, int N) {
  int row = blockIdx.x;
  const float4* a = (const float4*)(adj + (size_t)row * N);
  float s = 0.f;
  for (int j = threadIdx.x; j < N / 4; j += 256) {
    float4 v = a[j];
    s += v.x + v.y + v.z + v.w;
  }
#pragma unroll
  for (int off = 32; off > 0; off >>= 1) s += __shfl_down(s, off, 64);
  __shared__ float wsum[4];
  if ((threadIdx.x & 63) == 0) wsum[threadIdx.x >> 6] = s;
  __syncthreads();
  if (threadIdx.x == 0) {
    float t = wsum[0] + wsum[1] + wsum[2] + wsum[3];
    dis[row] = (t > 0.f) ? (1.0f / sqrtf(t)) : 0.f;
  }
}

// ---- fp32 -> bf16 vectorized ----------------------------------------------
__global__ void conv_bf16_k(const float* __restrict__ in, u16* __restrict__ o, int n4) {
  int i = blockIdx.x * 256 + threadIdx.x;
  if (i >= n4) return;
  float4 v = ((const float4*)in)[i];
  ushort4 u;
  u.x = f2bf(v.x); u.y = f2bf(v.y); u.z = f2bf(v.z); u.w = f2bf(v.w);
  ((ushort4*)o)[i] = u;
}

// ---- W [512,512] -> W^T bf16 ----------------------------------------------
__global__ void conv_wt_k(const float* __restrict__ w, u16* __restrict__ wt) {
  int idx = blockIdx.x * 256 + threadIdx.x;  // 262144 total
  int i = idx >> 9, o = idx & 511;
  wt[o * 512 + i] = f2bf(w[idx]);
}

// ---- norm_adj bf16 ---------------------------------------------------------
__global__ void make_nadj_k(const float* __restrict__ adj, const float* __restrict__ dis,
                            u16* __restrict__ o, int N) {
  int idx = blockIdx.x * 256 + threadIdx.x;  // per float4, N*N/4 total
  int i = idx >> 9;                          // N/4 = 512 float4 per row
  int j4 = (idx & 511) * 4;
  float di = dis[i];
  float4 a = ((const float4*)adj)[idx];
  ushort4 u;
  u.x = f2bf(a.x * di * dis[j4 + 0]);
  u.y = f2bf(a.y * di * dis[j4 + 1]);
  u.z = f2bf(a.z * di * dis[j4 + 2]);
  u.w = f2bf(a.w * di * dis[j4 + 3]);
  ((ushort4*)o)[idx] = u;
}

// ---- 256x256 bf16 GEMM, m201 8-phase / 2-K-tile iter, NO scheduling pins ---
// C = A[M,K] * Bt[N,K]^T. 512 threads (8 waves, 2Mx4N), BK=64, 128 KiB LDS
// double-buffered (E=even tiles slot0, O=odd tiles slot1), zero-conflict XOR
// swizzle (elem ^= (row&7)<<3, staging source + ds_read). Per phase:
// {in-phase ds_reads (0/4/8/12) + stage 1 half-tile (2 gloads) -> s_barrier ->
//  lgkmcnt(0) -> setprio(1) -> 16 MFMA -> setprio(0) -> barrier};
// vmcnt(6) only at phases 4 and 8 (3 half-tiles in flight), never 0 in-loop.
// Stage placement P1:A1(t1)->O, P2:A0/P3:B0/P4:B1/P5:A1 (t0+2)->E,
// P6:A0/P7:B0/P8:B1 (t1+2)->O -- every stage >=1 barrier after its region's
// last read (in-order lgkm + consuming MFMA), every read after its unit's
// vmcnt->barrier gate. NO sched_barrier(0) anywhere (m141: pins poison).
// EPI=0: bf16 C^T write; EPI=1: f32 C + bias.
template <int EPI>
__launch_bounds__(512, 2)
__global__ void gemm256_k(const u16* __restrict__ A, int lda,
                          const u16* __restrict__ Bt, int ldb,
                          void* __restrict__ Cv, int ldc,
                          const float* __restrict__ bias, int K,
                          int nMT, int nNT, size_t zBt, size_t zC) {
  __shared__ __align__(16) u16 lds[65536];  // A:[2][256][64] @0, B:[2][256][64] @32768

  const int tid = threadIdx.x;
  const int lane = tid & 63;
  const int wid = tid >> 6;
  const int wr = wid >> 2;   // 0..1  (M)
  const int wc = wid & 3;    // 0..3  (N)

  // bijective XCD swizzle (gridDim.x == 256, divisible by 8)
  const int flat = blockIdx.x;
  const int wg = (flat & 7) * ((int)gridDim.x >> 3) + (flat >> 3);
  const int m_t = wg % nMT;
  const int rest = wg / nMT;
  const int n_t = rest % nNT;
  const int b = rest / nNT;
  const int rowBase = m_t * 256;
  const int colBase = n_t * 256;
  const u16* Bb = Bt + (size_t)b * zBt;

  // staging: per-thread row lr, linear LDS col kkl, pre-swizzled global col
  const int lr = tid >> 3;            // 0..63
  const int kkl = (tid & 7) * 8;      // 0..56
  const int kswz = kkl ^ ((lr & 7) << 3);
  const u16* gA = A + (size_t)(rowBase + lr) * lda + kswz;
  const u16* gB = Bb + (size_t)(colBase + lr) * ldb + kswz;
  u16* lA = lds + lr * 64 + kkl;
  u16* lB = lds + 32768 + lr * 64 + kkl;

  // fragment reads: row = base + (lane&15); granule XOR on row bits 0-2
  const int fr = lane & 15;
  const int rswz = (lane & 7) << 3;
  const int kp0 = ((lane >> 4) * 8) ^ rswz;
  const int kp1 = (32 | ((lane >> 4) * 8)) ^ rswz;
  const u16* fA = lds + (wr * 128 + fr) * 64;
  const u16* fB = lds + 32768 + (wc * 64 + fr) * 64;

  f32x4 acc[8][4] = {};
  bf16x8 a0[4], a1[4], b0[4], b1[4];

  const int NT = K >> 6;
  const int NI = NT >> 1;  // 2 K-tiles per iteration (NT is even: K=512/2048)

// A-half h: rows {h*64..+63} U {h*64+128..+191} (= mh-h rows of both wr)
#define STAGE_A(d, h, t)                                                             \
  do {                                                                               \
    gload16(gA + (size_t)((h) * 64) * lda + (size_t)(t) * 64,                        \
            lA + (d) * 16384 + ((h) * 64) * 64);                                     \
    gload16(gA + (size_t)((h) * 64 + 128) * lda + (size_t)(t) * 64,                  \
            lA + (d) * 16384 + ((h) * 64 + 128) * 64);                               \
  } while (0)

// B-half h: rows h*128..+127
#define STAGE_B(d, h, t)                                                             \
  do {                                                                               \
    gload16(gB + (size_t)((h) * 128) * ldb + (size_t)(t) * 64,                       \
            lB + (d) * 16384 + ((h) * 128) * 64);                                    \
    gload16(gB + (size_t)((h) * 128 + 64) * ldb + (size_t)(t) * 64,                  \
            lB + (d) * 16384 + ((h) * 128 + 64) * 64);                               \
  } while (0)

#define RD_A8(mh, c)                                                                 \
  _Pragma("unroll") for (int m = 0; m < 4; ++m) {                                    \
    a0[m] = *(const bf16x8*)(fA + (c) * 16384 + (mh) * 4096 + m * 1024 + kp0);       \
    a1[m] = *(const bf16x8*)(fA + (c) * 16384 + (mh) * 4096 + m * 1024 + kp1);       \
  }

#define RD_B4(nlo, c)                                                                \
  _Pragma("unroll") for (int n = 0; n < 2; ++n) {                                    \
    b0[(nlo) + n] = *(const bf16x8*)(fB + (c) * 16384 + ((nlo) + n) * 1024 + kp0);   \
    b1[(nlo) + n] = *(const bf16x8*)(fB + (c) * 16384 + ((nlo) + n) * 1024 + kp1);   \
  }

#define MFMA16(mh, nlo)                                                              \
  __builtin_amdgcn_s_setprio(1);                                                     \
  _Pragma("unroll") for (int m = 0; m < 4; ++m) {                                    \
    _Pragma("unroll") for (int n = 0; n < 2; ++n) {                                  \
      acc[(mh) * 4 + m][(nlo) + n] = __builtin_amdgcn_mfma_f32_16x16x32_bf16(        \
          a0[m], b0[(nlo) + n], acc[(mh) * 4 + m][(nlo) + n], 0, 0, 0);              \
      acc[(mh) * 4 + m][(nlo) + n] = __builtin_amdgcn_mfma_f32_16x16x32_bf16(        \
          a1[m], b1[(nlo) + n], acc[(mh) * 4 + m][(nlo) + n], 0, 0, 0);              \
    }                                                                                \
  }                                                                                  \
  __builtin_amdgcn_s_setprio(0)

#define LGKM0() asm volatile("s_waitcnt lgkmcnt(0)" ::: "memory")
#define LGKM8() asm volatile("s_waitcnt lgkmcnt(8)" ::: "memory")
#define VM6()   asm volatile("s_waitcnt vmcnt(6)" ::: "memory")
#define BAR()   __builtin_amdgcn_s_barrier()

  // prologue: 7 units [tile0: A0 B0 B1 A1][tile1: A0 B0 B1]; vmcnt(6) -> tile0 landed
  {
    const int t1 = (NT > 1) ? 1 : 0;
    STAGE_A(0, 0, 0);
    STAGE_B(0, 0, 0);
    STAGE_B(0, 1, 0);
    STAGE_A(0, 1, 0);
    STAGE_A(1, 0, t1);
    STAGE_B(1, 0, t1);
    STAGE_B(1, 1, t1);
    VM6();
    BAR();
  }

  for (int i = 0; i < NI; ++i) {
    const int t1 = 2 * i + 1;                       // odd tile (real; NT even)
    const int s2 = (2 * i + 2 < NT) ? 2 * i + 2 : NT - 1;  // clamped tail stages
    const int s3 = (2 * i + 3 < NT) ? 2 * i + 3 : NT - 1;  // (land in dead regions)

    // ---- tile t0 = 2i from buffer E (slot 0) ----
    // P1: rd A(mh0)+B(n01); stage A1(t1)->O
    RD_A8(0, 0);
    RD_B4(0, 0);
    STAGE_A(1, 1, t1);
    LGKM8();
    BAR(); LGKM0();
    MFMA16(0, 0);
    BAR();

    // P2: rd B(n23); stage A0(t0+2)->E
    RD_B4(2, 0);
    STAGE_A(0, 0, s2);
    BAR(); LGKM0();
    MFMA16(0, 2);
    BAR();

    // P3: rd A(mh1); stage B0(t0+2)->E
    RD_A8(1, 0);
    STAGE_B(0, 0, s2);
    BAR(); LGKM0();
    MFMA16(1, 2);
    BAR();

    // P4: stage B1(t0+2)->E; vmcnt(6) gates tile t1 for P5-P8
    STAGE_B(0, 1, s2);
    BAR(); LGKM0();
    MFMA16(1, 0);
    VM6();
    BAR();

    // ---- tile t1 = 2i+1 from buffer O (slot 1) ----
    // P5: rd A(mh0)+B(n01); stage A1(t0+2)->E
    RD_A8(0, 1);
    RD_B4(0, 1);
    STAGE_A(0, 1, s2);
    LGKM8();
    BAR(); LGKM0();
    MFMA16(0, 0);
    BAR();

    // P6: rd B(n23); stage A0(t1+2)->O
    RD_B4(2, 1);
    STAGE_A(1, 0, s3);
    BAR(); LGKM0();
    MFMA16(0, 2);
    BAR();

    // P7: rd A(mh1); stage B0(t1+2)->O
    RD_A8(1, 1);
    STAGE_B(1, 0, s3);
    BAR(); LGKM0();
    MFMA16(1, 2);
    BAR();

    // P8: stage B1(t1+2)->O; vmcnt(6) gates tile t0+2 for next-iter P1-P4
    STAGE_B(1, 1, s3);
    BAR(); LGKM0();
    MFMA16(1, 0);
    VM6();
    BAR();
  }
  asm volatile("s_waitcnt vmcnt(0)" ::: "memory");  // drain clamped tail stages

  if (EPI == 0) {
    u16* C = (u16*)Cv;
#pragma unroll
    for (int am = 0; am < 8; ++am) {
      const int r = rowBase + wr * 128 + (am >> 2) * 64 + (am & 3) * 16 + (lane >> 4) * 4;
#pragma unroll
      for (int n = 0; n < 4; ++n) {
        const int cc = colBase + wc * 64 + n * 16 + (lane & 15);
        ushort4 v;
        v.x = f2bf(acc[am][n][0]);
        v.y = f2bf(acc[am][n][1]);
        v.z = f2bf(acc[am][n][2]);
        v.w = f2bf(acc[am][n][3]);
        *reinterpret_cast<ushort4*>(&C[(size_t)cc * ldc + r]) = v;
      }
    }
  } else {
    float* C = (float*)Cv + (size_t)b * zC;
#pragma unroll
    for (int n = 0; n < 4; ++n) {
      const int cc = colBase + wc * 64 + n * 16 + (lane & 15);
      const float bv = bias[cc];
#pragma unroll
      for (int am = 0; am < 8; ++am) {
        const int r = rowBase + wr * 128 + (am >> 2) * 64 + (am & 3) * 16 + (lane >> 4) * 4;
#pragma unroll
        for (int j = 0; j < 4; ++j)
          C[(size_t)(r + j) * ldc + cc] = acc[am][n][j] + bv;
      }
    }
  }
#undef STAGE_A
#undef STAGE_B
#undef RD_A8
#undef RD_B4
#undef MFMA16
#undef LGKM0
#undef LGKM8
#undef VM6
#undef BAR
}

extern "C" void kernel_launch(void* const* d_in, const int* in_sizes, int n_in,
                              void* d_out, int out_size, void* d_ws, size_t ws_size,
                              hipStream_t stream) {
  const int B = 16, N = 2048, FIN = 512, FOUT = 512;
  const float* x    = (const float*)d_in[0];
  const float* adj  = (const float*)d_in[1];
  const float* w    = (const float*)d_in[2];
  const float* bias = (const float*)d_in[3];
  float* out = (float*)d_out;
  char* ws = (char*)d_ws;

  float* dis = (float*)ws;                       // 8 KB
  u16* wt    = (u16*)(ws + 8192);                // 512 KB  W^T [FOUT][FIN]
  u16* nadj  = (u16*)(ws + 532480);              // 8 MB    [N][N]
  u16* xb    = (u16*)(ws + 8921088);             // 32 MB   [B*N][FIN]
  u16* st    = (u16*)(ws + 42475520);            // 32 MB   support^T [FOUT][B*N]

  row_deg_k<<<N, 256, 0, stream>>>(adj, dis, N);
  conv_bf16_k<<<(B * N * FIN / 4 + 255) / 256, 256, 0, stream>>>(x, xb, B * N * FIN / 4);
  conv_wt_k<<<(FIN * FOUT) / 256, 256, 0, stream>>>(w, wt);
  make_nadj_k<<<(N * N / 4) / 256, 256, 0, stream>>>(adj, dis, nadj, N);

  // GEMM1: support^T = (xb @ wt^T)^T : A=xb [32768,512], Bt=wt [512,512]
  // grid = 128*2*1 = 256 blocks
  gemm256_k<0><<<dim3(256), 512, 0, stream>>>(
      xb, FIN, wt, FIN, st, B * N, nullptr, FIN, 128, 2, 0, 0);

  // GEMM2: out[b] = nadj @ support[b] + bias : A=nadj [2048,2048],
  // Bt = st + b*2048 (ldb=32768, K=N), C = out + b*N*FOUT
  // grid = 8*2*16 = 256 blocks
  gemm256_k<1><<<dim3(256), 512, 0, stream>>>(
      nadj, N, st, B * N, out, FOUT, bias, N, 8, 2,
      (size_t)N, (size_t)N * FOUT);
}

// Round 9
// 116.735 us; speedup vs baseline: 1.0908x; 1.0663x over previous
//
#include <hip/hip_runtime.h>
#include <hip/hip_bf16.h>
#include <stdint.h>

typedef __attribute__((ext_vector_type(8))) __bf16 bf16x8;
typedef __attribute__((ext_vector_type(4))) float f32x4;
typedef unsigned short u16;

__device__ __forceinline__ u16 f2bf(float f) {
  unsigned u = __builtin_bit_cast(unsigned, f);
  unsigned r = 0x7FFFu + ((u >> 16) & 1u);
  return (u16)((u + r) >> 16);
}

__device__ __forceinline__ u16 f2bf_hw(float f) {
  __hip_bfloat16 h = __float2bfloat16(f);
  return __builtin_bit_cast(u16, h);
}

__device__ __forceinline__ void gload16(const void* g, void* l) {
  __builtin_amdgcn_global_load_lds(
      (__attribute__((address_space(1))) void*)(g),
      (__attribute__((address_space(3))) void*)(l),
      16, 0, 0);
}

// ---- deg / rsqrt -----------------------------------------------------------
__global__ void row_deg_k(const float* __restrict__ adj, float* __restrict__ dis, int N) {
  int row = blockIdx.x;
  const float4* a = (const float4*)(adj + (size_t)row * N);
  float s = 0.f;
  for (int j = threadIdx.x; j < N / 4; j += 256) {
    float4 v = a[j];
    s += v.x + v.y + v.z + v.w;
  }
#pragma unroll
  for (int off = 32; off > 0; off >>= 1) s += __shfl_down(s, off, 64);
  __shared__ float wsum[4];
  if ((threadIdx.x & 63) == 0) wsum[threadIdx.x >> 6] = s;
  __syncthreads();
  if (threadIdx.x == 0) {
    float t = wsum[0] + wsum[1] + wsum[2] + wsum[3];
    dis[row] = (t > 0.f) ? (1.0f / sqrtf(t)) : 0.f;
  }
}

// ---- W [512,512] -> W^T bf16 ----------------------------------------------
__global__ void conv_wt_k(const float* __restrict__ w, u16* __restrict__ wt) {
  int idx = blockIdx.x * 256 + threadIdx.x;  // 262144 total
  int i = idx >> 9, o = idx & 511;
  wt[o * 512 + i] = f2bf(w[idx]);
}

// ---- norm_adj bf16 ---------------------------------------------------------
__global__ void make_nadj_k(const float* __restrict__ adj, const float* __restrict__ dis,
                            u16* __restrict__ o, int N) {
  int idx = blockIdx.x * 256 + threadIdx.x;  // per float4, N*N/4 total
  int i = idx >> 9;                          // N/4 = 512 float4 per row
  int j4 = (idx & 511) * 4;
  float di = dis[i];
  float4 a = ((const float4*)adj)[idx];
  ushort4 u;
  u.x = f2bf(a.x * di * dis[j4 + 0]);
  u.y = f2bf(a.y * di * dis[j4 + 1]);
  u.z = f2bf(a.z * di * dis[j4 + 2]);
  u.w = f2bf(a.w * di * dis[j4 + 3]);
  ((ushort4*)o)[idx] = u;
}

// ---- GEMM1 (fused x-cast): Ct = (X @ Wt^T)^T ------------------------------
// X fp32 [M,512] row-major, Wt bf16 [512,512] ([o][i]), Ct bf16 [512][M].
// 256x256 tile, BK=64, 8 waves (2Mx4N), r7-style single-sync K-loop.
// A-path: reg-staged fp32 (issue-early at tile top, cvt+swizzled ds_write
// after the MFMA bulk -> HBM latency hidden under compute). B-path:
// global_load_lds with pre-swizzled source. Zero-conflict read swizzle
// elem ^= (row&7)<<3 on both tiles.
__launch_bounds__(512, 2)
__global__ void gemm1_xw_k(const float* __restrict__ X,
                           const u16* __restrict__ Wt,
                           u16* __restrict__ Ct, int M) {
  __shared__ __align__(16) u16 lds[65536];  // A:[2][256][64] @0, B:[2][256][64] @32768

  const int tid = threadIdx.x;
  const int lane = tid & 63;
  const int wid = tid >> 6;
  const int wr = wid >> 2;
  const int wc = wid & 3;

  // bijective XCD swizzle (256 blocks); nMT=128, nNT=2
  const int flat = blockIdx.x;
  const int wg = (flat & 7) * 32 + (flat >> 3);
  const int m_t = wg & 127;
  const int n_t = wg >> 7;
  const int rowBase = m_t * 256;
  const int colBase = n_t * 256;

  const int lr = tid >> 3;            // 0..63
  const int kkl = (tid & 7) * 8;      // 0..56
  const int s = (lr & 7) << 3;
  const int kswz = kkl ^ s;
  const float* gX = X + (size_t)(rowBase + lr) * 512 + kkl;     // unswizzled fp32
  const u16* gB = Wt + (size_t)(colBase + lr) * 512 + kswz;     // pre-swizzled src
  u16* lAsw = lds + lr * 64 + kswz;   // swizzled LDS dest (reg path)
  u16* lB = lds + 32768 + lr * 64 + kkl;

  const int fr = lane & 15;
  const int rswz = (lane & 7) << 3;
  const int kp0 = ((lane >> 4) * 8) ^ rswz;
  const int kp1 = (32 | ((lane >> 4) * 8)) ^ rswz;
  const u16* fA = lds + (wr * 128 + fr) * 64;
  const u16* fB = lds + 32768 + (wc * 64 + fr) * 64;

  f32x4 acc[8][4] = {};
  f32x4 xv[4][2];

  const int NT = 8;  // K = 512

#define LOADX(t)                                                                     \
  _Pragma("unroll") for (int r4 = 0; r4 < 4; ++r4) {                                 \
    xv[r4][0] = *(const f32x4*)(gX + (size_t)(r4 * 64) * 512 + (t) * 64);            \
    xv[r4][1] = *(const f32x4*)(gX + (size_t)(r4 * 64) * 512 + (t) * 64 + 4);        \
  }

#define STAGE_B1(d, t)                                                               \
  _Pragma("unroll") for (int r4 = 0; r4 < 4; ++r4)                                   \
    gload16(gB + (size_t)(r4 * 64) * 512 + (size_t)(t) * 64,                         \
            lB + (d) * 16384 + r4 * 4096);

#define WRITE_A(d)                                                                   \
  _Pragma("unroll") for (int r4 = 0; r4 < 4; ++r4) {                                 \
    bf16x8 v;                                                                        \
    _Pragma("unroll") for (int i = 0; i < 4; ++i) {                                  \
      v[i] = __builtin_bit_cast(__bf16, f2bf_hw(xv[r4][0][i]));                      \
      v[4 + i] = __builtin_bit_cast(__bf16, f2bf_hw(xv[r4][1][i]));                  \
    }                                                                                \
    *(bf16x8*)(lAsw + (d) * 16384 + r4 * 4096) = v;                                  \
  }

  // prologue
  LOADX(0);
  STAGE_B1(0, 0);
  WRITE_A(0);
  __syncthreads();

  for (int t = 0; t < NT; ++t) {
    const int c = t & 1;
    const int cn = c ^ 1;
    const int tn = (t + 1 < NT) ? t + 1 : NT - 1;

    LOADX(tn);
    STAGE_B1(cn, tn);
    __builtin_amdgcn_sched_barrier(0);   // pin issue-early block at top

    bf16x8 a0[8], a1[8], b0[4], b1[4];
#pragma unroll
    for (int m = 0; m < 8; ++m) {
      a0[m] = *(const bf16x8*)(fA + c * 16384 + m * 1024 + kp0);
      a1[m] = *(const bf16x8*)(fA + c * 16384 + m * 1024 + kp1);
    }
#pragma unroll
    for (int n = 0; n < 4; ++n) {
      b0[n] = *(const bf16x8*)(fB + c * 16384 + n * 1024 + kp0);
      b1[n] = *(const bf16x8*)(fB + c * 16384 + n * 1024 + kp1);
    }
#pragma unroll
    for (int m = 0; m < 8; ++m)
#pragma unroll
      for (int n = 0; n < 4; ++n)
        acc[m][n] = __builtin_amdgcn_mfma_f32_16x16x32_bf16(a0[m], b0[n], acc[m][n], 0, 0, 0);
#pragma unroll
    for (int m = 0; m < 8; ++m)
#pragma unroll
      for (int n = 0; n < 4; ++n)
        acc[m][n] = __builtin_amdgcn_mfma_f32_16x16x32_bf16(a1[m], b1[n], acc[m][n], 0, 0, 0);

    __builtin_amdgcn_sched_barrier(0);   // keep write-late block below MFMAs
    WRITE_A(cn);
    __syncthreads();
  }

  // epilogue: bf16 C^T write, ldc = M
#pragma unroll
  for (int m = 0; m < 8; ++m) {
    const int r = rowBase + wr * 128 + m * 16 + (lane >> 4) * 4;
#pragma unroll
    for (int n = 0; n < 4; ++n) {
      const int cc = colBase + wc * 64 + n * 16 + (lane & 15);
      ushort4 v;
      v.x = f2bf(acc[m][n][0]);
      v.y = f2bf(acc[m][n][1]);
      v.z = f2bf(acc[m][n][2]);
      v.w = f2bf(acc[m][n][3]);
      *reinterpret_cast<ushort4*>(&Ct[(size_t)cc * M + r]) = v;
    }
  }
#undef LOADX
#undef STAGE_B1
#undef WRITE_A
}

// ---- GEMM2: 256x256 bf16, m201 8-phase / 2-K-tile iter (r8, unchanged) -----
__launch_bounds__(512, 2)
__global__ void gemm2_k(const u16* __restrict__ A, int lda,
                        const u16* __restrict__ Bt, int ldb,
                        float* __restrict__ C, int ldc,
                        const float* __restrict__ bias, int K,
                        int nMT, int nNT, size_t zBt, size_t zC) {
  __shared__ __align__(16) u16 lds[65536];  // A:[2][256][64] @0, B:[2][256][64] @32768

  const int tid = threadIdx.x;
  const int lane = tid & 63;
  const int wid = tid >> 6;
  const int wr = wid >> 2;
  const int wc = wid & 3;

  const int flat = blockIdx.x;
  const int wg = (flat & 7) * ((int)gridDim.x >> 3) + (flat >> 3);
  const int m_t = wg % nMT;
  const int rest = wg / nMT;
  const int n_t = rest % nNT;
  const int b = rest / nNT;
  const int rowBase = m_t * 256;
  const int colBase = n_t * 256;
  const u16* Bb = Bt + (size_t)b * zBt;

  const int lr = tid >> 3;
  const int kkl = (tid & 7) * 8;
  const int kswz = kkl ^ ((lr & 7) << 3);
  const u16* gA = A + (size_t)(rowBase + lr) * lda + kswz;
  const u16* gB = Bb + (size_t)(colBase + lr) * ldb + kswz;
  u16* lA = lds + lr * 64 + kkl;
  u16* lB = lds + 32768 + lr * 64 + kkl;

  const int fr = lane & 15;
  const int rswz = (lane & 7) << 3;
  const int kp0 = ((lane >> 4) * 8) ^ rswz;
  const int kp1 = (32 | ((lane >> 4) * 8)) ^ rswz;
  const u16* fA = lds + (wr * 128 + fr) * 64;
  const u16* fB = lds + 32768 + (wc * 64 + fr) * 64;

  f32x4 acc[8][4] = {};
  bf16x8 a0[4], a1[4], b0[4], b1[4];

  const int NT = K >> 6;
  const int NI = NT >> 1;

#define STAGE_A(d, h, t)                                                             \
  do {                                                                               \
    gload16(gA + (size_t)((h) * 64) * lda + (size_t)(t) * 64,                        \
            lA + (d) * 16384 + ((h) * 64) * 64);                                     \
    gload16(gA + (size_t)((h) * 64 + 128) * lda + (size_t)(t) * 64,                  \
            lA + (d) * 16384 + ((h) * 64 + 128) * 64);                               \
  } while (0)

#define STAGE_B(d, h, t)                                                             \
  do {                                                                               \
    gload16(gB + (size_t)((h) * 128) * ldb + (size_t)(t) * 64,                       \
            lB + (d) * 16384 + ((h) * 128) * 64);                                    \
    gload16(gB + (size_t)((h) * 128 + 64) * ldb + (size_t)(t) * 64,                  \
            lB + (d) * 16384 + ((h) * 128 + 64) * 64);                               \
  } while (0)

#define RD_A8(mh, c)                                                                 \
  _Pragma("unroll") for (int m = 0; m < 4; ++m) {                                    \
    a0[m] = *(const bf16x8*)(fA + (c) * 16384 + (mh) * 4096 + m * 1024 + kp0);       \
    a1[m] = *(const bf16x8*)(fA + (c) * 16384 + (mh) * 4096 + m * 1024 + kp1);       \
  }

#define RD_B4(nlo, c)                                                                \
  _Pragma("unroll") for (int n = 0; n < 2; ++n) {                                    \
    b0[(nlo) + n] = *(const bf16x8*)(fB + (c) * 16384 + ((nlo) + n) * 1024 + kp0);   \
    b1[(nlo) + n] = *(const bf16x8*)(fB + (c) * 16384 + ((nlo) + n) * 1024 + kp1);   \
  }

#define MFMA16(mh, nlo)                                                              \
  __builtin_amdgcn_s_setprio(1);                                                     \
  _Pragma("unroll") for (int m = 0; m < 4; ++m) {                                    \
    _Pragma("unroll") for (int n = 0; n < 2; ++n) {                                  \
      acc[(mh) * 4 + m][(nlo) + n] = __builtin_amdgcn_mfma_f32_16x16x32_bf16(        \
          a0[m], b0[(nlo) + n], acc[(mh) * 4 + m][(nlo) + n], 0, 0, 0);              \
      acc[(mh) * 4 + m][(nlo) + n] = __builtin_amdgcn_mfma_f32_16x16x32_bf16(        \
          a1[m], b1[(nlo) + n], acc[(mh) * 4 + m][(nlo) + n], 0, 0, 0);              \
    }                                                                                \
  }                                                                                  \
  __builtin_amdgcn_s_setprio(0)

#define LGKM0() asm volatile("s_waitcnt lgkmcnt(0)" ::: "memory")
#define LGKM8() asm volatile("s_waitcnt lgkmcnt(8)" ::: "memory")
#define VM6()   asm volatile("s_waitcnt vmcnt(6)" ::: "memory")
#define BAR()   __builtin_amdgcn_s_barrier()

  {
    const int t1 = (NT > 1) ? 1 : 0;
    STAGE_A(0, 0, 0);
    STAGE_B(0, 0, 0);
    STAGE_B(0, 1, 0);
    STAGE_A(0, 1, 0);
    STAGE_A(1, 0, t1);
    STAGE_B(1, 0, t1);
    STAGE_B(1, 1, t1);
    VM6();
    BAR();
  }

  for (int i = 0; i < NI; ++i) {
    const int t1 = 2 * i + 1;
    const int s2 = (2 * i + 2 < NT) ? 2 * i + 2 : NT - 1;
    const int s3 = (2 * i + 3 < NT) ? 2 * i + 3 : NT - 1;

    RD_A8(0, 0);
    RD_B4(0, 0);
    STAGE_A(1, 1, t1);
    LGKM8();
    BAR(); LGKM0();
    MFMA16(0, 0);
    BAR();

    RD_B4(2, 0);
    STAGE_A(0, 0, s2);
    BAR(); LGKM0();
    MFMA16(0, 2);
    BAR();

    RD_A8(1, 0);
    STAGE_B(0, 0, s2);
    BAR(); LGKM0();
    MFMA16(1, 2);
    BAR();

    STAGE_B(0, 1, s2);
    BAR(); LGKM0();
    MFMA16(1, 0);
    VM6();
    BAR();

    RD_A8(0, 1);
    RD_B4(0, 1);
    STAGE_A(0, 1, s2);
    LGKM8();
    BAR(); LGKM0();
    MFMA16(0, 0);
    BAR();

    RD_B4(2, 1);
    STAGE_A(1, 0, s3);
    BAR(); LGKM0();
    MFMA16(0, 2);
    BAR();

    RD_A8(1, 1);
    STAGE_B(1, 0, s3);
    BAR(); LGKM0();
    MFMA16(1, 2);
    BAR();

    STAGE_B(1, 1, s3);
    BAR(); LGKM0();
    MFMA16(1, 0);
    VM6();
    BAR();
  }
  asm volatile("s_waitcnt vmcnt(0)" ::: "memory");

  // epilogue: f32 C + bias
#pragma unroll
  for (int n = 0; n < 4; ++n) {
    const int cc = colBase + wc * 64 + n * 16 + (lane & 15);
    const float bv = bias[cc];
#pragma unroll
    for (int am = 0; am < 8; ++am) {
      const int r = rowBase + wr * 128 + (am >> 2) * 64 + (am & 3) * 16 + (lane >> 4) * 4;
#pragma unroll
      for (int j = 0; j < 4; ++j)
        C[(size_t)b * zC + (size_t)(r + j) * ldc + cc] = acc[am][n][j] + bv;
    }
  }
#undef STAGE_A
#undef STAGE_B
#undef RD_A8
#undef RD_B4
#undef MFMA16
#undef LGKM0
#undef LGKM8
#undef VM6
#undef BAR
}

extern "C" void kernel_launch(void* const* d_in, const int* in_sizes, int n_in,
                              void* d_out, int out_size, void* d_ws, size_t ws_size,
                              hipStream_t stream) {
  const int B = 16, N = 2048, FIN = 512, FOUT = 512;
  const float* x    = (const float*)d_in[0];
  const float* adj  = (const float*)d_in[1];
  const float* w    = (const float*)d_in[2];
  const float* bias = (const float*)d_in[3];
  float* out = (float*)d_out;
  char* ws = (char*)d_ws;

  float* dis = (float*)ws;                       // 8 KB
  u16* wt    = (u16*)(ws + 8192);                // 512 KB  W^T [FOUT][FIN]
  u16* nadj  = (u16*)(ws + 532480);              // 8 MB    [N][N]
  u16* st    = (u16*)(ws + 8921088);             // 32 MB   support^T [FOUT][B*N]

  row_deg_k<<<N, 256, 0, stream>>>(adj, dis, N);
  conv_wt_k<<<(FIN * FOUT) / 256, 256, 0, stream>>>(w, wt);
  make_nadj_k<<<(N * N / 4) / 256, 256, 0, stream>>>(adj, dis, nadj, N);

  // GEMM1 (fused x->bf16): st = (x @ wt^T)^T ; grid 128*2 = 256 blocks
  gemm1_xw_k<<<dim3(256), 512, 0, stream>>>(x, wt, st, B * N);

  // GEMM2: out[b] = nadj @ support[b] + bias ; grid 8*2*16 = 256 blocks
  gemm2_k<<<dim3(256), 512, 0, stream>>>(
      nadj, N, st, B * N, out, FOUT, bias, N, 8, 2,
      (size_t)N, (size_t)N * FOUT);
}

// Round 10
// 115.884 us; speedup vs baseline: 1.0988x; 1.0073x over previous
//
#include <hip/hip_runtime.h>
#include <hip/hip_bf16.h>
#include <stdint.h>

typedef __attribute__((ext_vector_type(8))) __bf16 bf16x8;
typedef __attribute__((ext_vector_type(4))) float f32x4;
typedef unsigned short u16;

__device__ __forceinline__ u16 f2bf(float f) {
  unsigned u = __builtin_bit_cast(unsigned, f);
  unsigned r = 0x7FFFu + ((u >> 16) & 1u);
  return (u16)((u + r) >> 16);
}

__device__ __forceinline__ u16 f2bf_hw(float f) {
  __hip_bfloat16 h = __float2bfloat16(f);
  return __builtin_bit_cast(u16, h);
}

__device__ __forceinline__ void gload16(const void* g, void* l) {
  __builtin_amdgcn_global_load_lds(
      (__attribute__((address_space(1))) void*)(g),
      (__attribute__((address_space(3))) void*)(l),
      16, 0, 0);
}

// ---- deg / rsqrt -----------------------------------------------------------
__global__ void row_deg_k(const float* __restrict__ adj, float* __restrict__ dis, int N) {
  int row = blockIdx.x;
  const float4* a = (const float4*)(adj + (size_t)row * N);
  float s = 0.f;
  for (int j = threadIdx.x; j < N / 4; j += 256) {
    float4 v = a[j];
    s += v.x + v.y + v.z + v.w;
  }
#pragma unroll
  for (int off = 32; off > 0; off >>= 1) s += __shfl_down(s, off, 64);
  __shared__ float wsum[4];
  if ((threadIdx.x & 63) == 0) wsum[threadIdx.x >> 6] = s;
  __syncthreads();
  if (threadIdx.x == 0) {
    float t = wsum[0] + wsum[1] + wsum[2] + wsum[3];
    dis[row] = (t > 0.f) ? (1.0f / sqrtf(t)) : 0.f;
  }
}

// ---- W [512,512] -> W^T bf16 ----------------------------------------------
__global__ void conv_wt_k(const float* __restrict__ w, u16* __restrict__ wt) {
  int idx = blockIdx.x * 256 + threadIdx.x;  // 262144 total
  int i = idx >> 9, o = idx & 511;
  wt[o * 512 + i] = f2bf(w[idx]);
}

// ---- norm_adj bf16 ---------------------------------------------------------
__global__ void make_nadj_k(const float* __restrict__ adj, const float* __restrict__ dis,
                            u16* __restrict__ o, int N) {
  int idx = blockIdx.x * 256 + threadIdx.x;  // per float4, N*N/4 total
  int i = idx >> 9;                          // N/4 = 512 float4 per row
  int j4 = (idx & 511) * 4;
  float di = dis[i];
  float4 a = ((const float4*)adj)[idx];
  ushort4 u;
  u.x = f2bf(a.x * di * dis[j4 + 0]);
  u.y = f2bf(a.y * di * dis[j4 + 1]);
  u.z = f2bf(a.z * di * dis[j4 + 2]);
  u.w = f2bf(a.w * di * dis[j4 + 3]);
  ((ushort4*)o)[idx] = u;
}

// ---- GEMM1 (fused x-cast): Ct = (X @ Wt^T)^T (r9, unchanged) ---------------
__launch_bounds__(512, 2)
__global__ void gemm1_xw_k(const float* __restrict__ X,
                           const u16* __restrict__ Wt,
                           u16* __restrict__ Ct, int M) {
  __shared__ __align__(16) u16 lds[65536];

  const int tid = threadIdx.x;
  const int lane = tid & 63;
  const int wid = tid >> 6;
  const int wr = wid >> 2;
  const int wc = wid & 3;

  const int flat = blockIdx.x;
  const int wg = (flat & 7) * 32 + (flat >> 3);
  const int m_t = wg & 127;
  const int n_t = wg >> 7;
  const int rowBase = m_t * 256;
  const int colBase = n_t * 256;

  const int lr = tid >> 3;
  const int kkl = (tid & 7) * 8;
  const int s = (lr & 7) << 3;
  const int kswz = kkl ^ s;
  const float* gX = X + (size_t)(rowBase + lr) * 512 + kkl;
  const u16* gB = Wt + (size_t)(colBase + lr) * 512 + kswz;
  u16* lAsw = lds + lr * 64 + kswz;
  u16* lB = lds + 32768 + lr * 64 + kkl;

  const int fr = lane & 15;
  const int rswz = (lane & 7) << 3;
  const int kp0 = ((lane >> 4) * 8) ^ rswz;
  const int kp1 = (32 | ((lane >> 4) * 8)) ^ rswz;
  const u16* fA = lds + (wr * 128 + fr) * 64;
  const u16* fB = lds + 32768 + (wc * 64 + fr) * 64;

  f32x4 acc[8][4] = {};
  f32x4 xv[4][2];

  const int NT = 8;  // K = 512

#define LOADX(t)                                                                     \
  _Pragma("unroll") for (int r4 = 0; r4 < 4; ++r4) {                                 \
    xv[r4][0] = *(const f32x4*)(gX + (size_t)(r4 * 64) * 512 + (t) * 64);            \
    xv[r4][1] = *(const f32x4*)(gX + (size_t)(r4 * 64) * 512 + (t) * 64 + 4);        \
  }

#define STAGE_B1(d, t)                                                               \
  _Pragma("unroll") for (int r4 = 0; r4 < 4; ++r4)                                   \
    gload16(gB + (size_t)(r4 * 64) * 512 + (size_t)(t) * 64,                         \
            lB + (d) * 16384 + r4 * 4096);

#define WRITE_A(d)                                                                   \
  _Pragma("unroll") for (int r4 = 0; r4 < 4; ++r4) {                                 \
    bf16x8 v;                                                                        \
    _Pragma("unroll") for (int i = 0; i < 4; ++i) {                                  \
      v[i] = __builtin_bit_cast(__bf16, f2bf_hw(xv[r4][0][i]));                      \
      v[4 + i] = __builtin_bit_cast(__bf16, f2bf_hw(xv[r4][1][i]));                  \
    }                                                                                \
    *(bf16x8*)(lAsw + (d) * 16384 + r4 * 4096) = v;                                  \
  }

  LOADX(0);
  STAGE_B1(0, 0);
  WRITE_A(0);
  __syncthreads();

  for (int t = 0; t < NT; ++t) {
    const int c = t & 1;
    const int cn = c ^ 1;
    const int tn = (t + 1 < NT) ? t + 1 : NT - 1;

    LOADX(tn);
    STAGE_B1(cn, tn);
    __builtin_amdgcn_sched_barrier(0);

    bf16x8 a0[8], a1[8], b0[4], b1[4];
#pragma unroll
    for (int m = 0; m < 8; ++m) {
      a0[m] = *(const bf16x8*)(fA + c * 16384 + m * 1024 + kp0);
      a1[m] = *(const bf16x8*)(fA + c * 16384 + m * 1024 + kp1);
    }
#pragma unroll
    for (int n = 0; n < 4; ++n) {
      b0[n] = *(const bf16x8*)(fB + c * 16384 + n * 1024 + kp0);
      b1[n] = *(const bf16x8*)(fB + c * 16384 + n * 1024 + kp1);
    }
#pragma unroll
    for (int m = 0; m < 8; ++m)
#pragma unroll
      for (int n = 0; n < 4; ++n)
        acc[m][n] = __builtin_amdgcn_mfma_f32_16x16x32_bf16(a0[m], b0[n], acc[m][n], 0, 0, 0);
#pragma unroll
    for (int m = 0; m < 8; ++m)
#pragma unroll
      for (int n = 0; n < 4; ++n)
        acc[m][n] = __builtin_amdgcn_mfma_f32_16x16x32_bf16(a1[m], b1[n], acc[m][n], 0, 0, 0);

    __builtin_amdgcn_sched_barrier(0);
    WRITE_A(cn);
    __syncthreads();
  }

#pragma unroll
  for (int m = 0; m < 8; ++m) {
    const int r = rowBase + wr * 128 + m * 16 + (lane >> 4) * 4;
#pragma unroll
    for (int n = 0; n < 4; ++n) {
      const int cc = colBase + wc * 64 + n * 16 + (lane & 15);
      ushort4 v;
      v.x = f2bf(acc[m][n][0]);
      v.y = f2bf(acc[m][n][1]);
      v.z = f2bf(acc[m][n][2]);
      v.w = f2bf(acc[m][n][3]);
      *reinterpret_cast<ushort4*>(&Ct[(size_t)cc * M + r]) = v;
    }
  }
#undef LOADX
#undef STAGE_B1
#undef WRITE_A
}

// ---- GEMM2: 128x256 tile, BK=64, single-buffer, 2 blocks/CU (TLP) ----------
// C = A[M,K] * Bt[N,K]^T, f32 out + bias. 512 threads (8 waves, 2Mx4N),
// wave = 64x64 out, 48 KiB LDS (A [128][64] @0, B [256][64] @8192 u16).
// Zero-conflict swizzle elem ^= (row&7)<<3 (rows are 128B). r1-proven
// 2-sync loop; cross-block TLP (2 resident blocks/CU, desynced barriers)
// provides the LDS<->MFMA overlap intra-block schedules couldn't.
__launch_bounds__(512, 4)
__global__ void gemm2b_k(const u16* __restrict__ A, int lda,
                         const u16* __restrict__ Bt, int ldb,
                         float* __restrict__ C, int ldc,
                         const float* __restrict__ bias, int K,
                         int nMT, int nNT, size_t zBt, size_t zC) {
  __shared__ __align__(16) u16 lds[24576];  // 48 KiB

  const int tid = threadIdx.x;
  const int lane = tid & 63;
  const int wid = tid >> 6;
  const int wr = wid >> 2;   // 0..1  (M, 64-row slabs)
  const int wc = wid & 3;    // 0..3  (N, 64-col slabs)

  // bijective XCD swizzle (gridDim.x = 512, divisible by 8)
  const int flat = blockIdx.x;
  const int cpx = (int)gridDim.x >> 3;
  const int wg = (flat & 7) * cpx + (flat >> 3);
  const int m_t = wg % nMT;
  const int rest = wg / nMT;
  const int n_t = rest % nNT;
  const int b = rest / nNT;
  const int rowBase = m_t * 128;
  const int colBase = n_t * 256;
  const u16* Bb = Bt + (size_t)b * zBt;

  // staging: row lr (0..63), col kkl; pre-swizzled global col
  const int lr = tid >> 3;
  const int kkl = (tid & 7) * 8;
  const int kswz = kkl ^ ((lr & 7) << 3);
  const u16* gA = A + (size_t)(rowBase + lr) * lda + kswz;
  const u16* gB = Bb + (size_t)(colBase + lr) * ldb + kswz;
  u16* lA = lds + lr * 64 + kkl;
  u16* lB = lds + 8192 + lr * 64 + kkl;

  // fragment reads
  const int fr = lane & 15;
  const int rswz = (lane & 7) << 3;
  const int kp0 = ((lane >> 4) * 8) ^ rswz;
  const int kp1 = (32 | ((lane >> 4) * 8)) ^ rswz;
  const u16* fA = lds + (wr * 64 + fr) * 64;
  const u16* fB = lds + 8192 + (wc * 64 + fr) * 64;

  f32x4 acc[4][4] = {};
  const int NT = K >> 6;

  for (int t = 0; t < NT; ++t) {
    // stage tile t: A 2 gloads + B 4 gloads per thread (48 KiB total)
    gload16(gA + (size_t)t * 64, lA);
    gload16(gA + (size_t)64 * lda + (size_t)t * 64, lA + 4096);
#pragma unroll
    for (int r4 = 0; r4 < 4; ++r4)
      gload16(gB + (size_t)(r4 * 64) * ldb + (size_t)t * 64, lB + r4 * 4096);
    __syncthreads();  // full vm+lgkm drain + barrier: tile published

    bf16x8 a[4], bb[4];
#pragma unroll
    for (int m = 0; m < 4; ++m) a[m] = *(const bf16x8*)(fA + m * 1024 + kp0);
#pragma unroll
    for (int n = 0; n < 4; ++n) bb[n] = *(const bf16x8*)(fB + n * 1024 + kp0);
#pragma unroll
    for (int m = 0; m < 4; ++m)
#pragma unroll
      for (int n = 0; n < 4; ++n)
        acc[m][n] = __builtin_amdgcn_mfma_f32_16x16x32_bf16(a[m], bb[n], acc[m][n], 0, 0, 0);
#pragma unroll
    for (int m = 0; m < 4; ++m) a[m] = *(const bf16x8*)(fA + m * 1024 + kp1);
#pragma unroll
    for (int n = 0; n < 4; ++n) bb[n] = *(const bf16x8*)(fB + n * 1024 + kp1);
#pragma unroll
    for (int m = 0; m < 4; ++m)
#pragma unroll
      for (int n = 0; n < 4; ++n)
        acc[m][n] = __builtin_amdgcn_mfma_f32_16x16x32_bf16(a[m], bb[n], acc[m][n], 0, 0, 0);

    __syncthreads();  // all reads consumed before next stage overwrites
  }

  // epilogue: f32 C + bias
  float* Cb = C + (size_t)b * zC;
#pragma unroll
  for (int n = 0; n < 4; ++n) {
    const int cc = colBase + wc * 64 + n * 16 + (lane & 15);
    const float bv = bias[cc];
#pragma unroll
    for (int m = 0; m < 4; ++m) {
      const int r = rowBase + wr * 64 + m * 16 + (lane >> 4) * 4;
#pragma unroll
      for (int j = 0; j < 4; ++j)
        Cb[(size_t)(r + j) * ldc + cc] = acc[m][n][j] + bv;
    }
  }
}

extern "C" void kernel_launch(void* const* d_in, const int* in_sizes, int n_in,
                              void* d_out, int out_size, void* d_ws, size_t ws_size,
                              hipStream_t stream) {
  const int B = 16, N = 2048, FIN = 512, FOUT = 512;
  const float* x    = (const float*)d_in[0];
  const float* adj  = (const float*)d_in[1];
  const float* w    = (const float*)d_in[2];
  const float* bias = (const float*)d_in[3];
  float* out = (float*)d_out;
  char* ws = (char*)d_ws;

  float* dis = (float*)ws;                       // 8 KB
  u16* wt    = (u16*)(ws + 8192);                // 512 KB  W^T [FOUT][FIN]
  u16* nadj  = (u16*)(ws + 532480);              // 8 MB    [N][N]
  u16* st    = (u16*)(ws + 8921088);             // 32 MB   support^T [FOUT][B*N]

  row_deg_k<<<N, 256, 0, stream>>>(adj, dis, N);
  conv_wt_k<<<(FIN * FOUT) / 256, 256, 0, stream>>>(w, wt);
  make_nadj_k<<<(N * N / 4) / 256, 256, 0, stream>>>(adj, dis, nadj, N);

  // GEMM1 (fused x->bf16): st = (x @ wt^T)^T ; grid 128*2 = 256 blocks
  gemm1_xw_k<<<dim3(256), 512, 0, stream>>>(x, wt, st, B * N);

  // GEMM2: out[b] = nadj @ support[b] + bias ; grid 16*2*16 = 512 blocks (2/CU)
  gemm2b_k<<<dim3(512), 512, 0, stream>>>(
      nadj, N, st, B * N, out, FOUT, bias, N, 16, 2,
      (size_t)N, (size_t)N * FOUT);
}

// Round 11
// 111.855 us; speedup vs baseline: 1.1384x; 1.0360x over previous
//
#include <hip/hip_runtime.h>
#include <hip/hip_bf16.h>
#include <stdint.h>

typedef __attribute__((ext_vector_type(8))) __bf16 bf16x8;
typedef __attribute__((ext_vector_type(4))) float f32x4;
typedef unsigned short u16;

__device__ __forceinline__ u16 f2bf(float f) {
  unsigned u = __builtin_bit_cast(unsigned, f);
  unsigned r = 0x7FFFu + ((u >> 16) & 1u);
  return (u16)((u + r) >> 16);
}

__device__ __forceinline__ u16 f2bf_hw(float f) {
  __hip_bfloat16 h = __float2bfloat16(f);
  return __builtin_bit_cast(u16, h);
}

__device__ __forceinline__ void gload16(const void* g, void* l) {
  __builtin_amdgcn_global_load_lds(
      (__attribute__((address_space(1))) void*)(g),
      (__attribute__((address_space(3))) void*)(l),
      16, 0, 0);
}

// ---- deg / rsqrt -----------------------------------------------------------
__global__ void row_deg_k(const float* __restrict__ adj, float* __restrict__ dis, int N) {
  int row = blockIdx.x;
  const float4* a = (const float4*)(adj + (size_t)row * N);
  float s = 0.f;
  for (int j = threadIdx.x; j < N / 4; j += 256) {
    float4 v = a[j];
    s += v.x + v.y + v.z + v.w;
  }
#pragma unroll
  for (int off = 32; off > 0; off >>= 1) s += __shfl_down(s, off, 64);
  __shared__ float wsum[4];
  if ((threadIdx.x & 63) == 0) wsum[threadIdx.x >> 6] = s;
  __syncthreads();
  if (threadIdx.x == 0) {
    float t = wsum[0] + wsum[1] + wsum[2] + wsum[3];
    dis[row] = (t > 0.f) ? (1.0f / sqrtf(t)) : 0.f;
  }
}

// ---- W [512,512] -> W^T bf16 ----------------------------------------------
__global__ void conv_wt_k(const float* __restrict__ w, u16* __restrict__ wt) {
  int idx = blockIdx.x * 256 + threadIdx.x;  // 262144 total
  int i = idx >> 9, o = idx & 511;
  wt[o * 512 + i] = f2bf(w[idx]);
}

// ---- norm_adj bf16 ---------------------------------------------------------
__global__ void make_nadj_k(const float* __restrict__ adj, const float* __restrict__ dis,
                            u16* __restrict__ o, int N) {
  int idx = blockIdx.x * 256 + threadIdx.x;  // per float4, N*N/4 total
  int i = idx >> 9;                          // N/4 = 512 float4 per row
  int j4 = (idx & 511) * 4;
  float di = dis[i];
  float4 a = ((const float4*)adj)[idx];
  ushort4 u;
  u.x = f2bf(a.x * di * dis[j4 + 0]);
  u.y = f2bf(a.y * di * dis[j4 + 1]);
  u.z = f2bf(a.z * di * dis[j4 + 2]);
  u.w = f2bf(a.w * di * dis[j4 + 3]);
  ((ushort4*)o)[idx] = u;
}

// ---- GEMM1 (fused x-cast): Ct = (X @ Wt^T)^T -------------------------------
// r9/r10 structure; ONE CHANGE: block mapping pairs the two n-tiles of each
// m-tile on adjacent wg (same XCD chunk) so the shared X-slab (512 KB) is
// fetched from HBM once and L2-hits for the sibling block (was: different
// XCDs -> X read twice from HBM, ~+64 MB).
__launch_bounds__(512, 2)
__global__ void gemm1_xw_k(const float* __restrict__ X,
                           const u16* __restrict__ Wt,
                           u16* __restrict__ Ct, int M) {
  __shared__ __align__(16) u16 lds[65536];

  const int tid = threadIdx.x;
  const int lane = tid & 63;
  const int wid = tid >> 6;
  const int wr = wid >> 2;
  const int wc = wid & 3;

  const int flat = blockIdx.x;
  const int wg = (flat & 7) * 32 + (flat >> 3);
  const int m_t = wg >> 1;   // n-pair of one m-tile are wg,wg+1: same XCD chunk
  const int n_t = wg & 1;
  const int rowBase = m_t * 256;
  const int colBase = n_t * 256;

  const int lr = tid >> 3;
  const int kkl = (tid & 7) * 8;
  const int s = (lr & 7) << 3;
  const int kswz = kkl ^ s;
  const float* gX = X + (size_t)(rowBase + lr) * 512 + kkl;
  const u16* gB = Wt + (size_t)(colBase + lr) * 512 + kswz;
  u16* lAsw = lds + lr * 64 + kswz;
  u16* lB = lds + 32768 + lr * 64 + kkl;

  const int fr = lane & 15;
  const int rswz = (lane & 7) << 3;
  const int kp0 = ((lane >> 4) * 8) ^ rswz;
  const int kp1 = (32 | ((lane >> 4) * 8)) ^ rswz;
  const u16* fA = lds + (wr * 128 + fr) * 64;
  const u16* fB = lds + 32768 + (wc * 64 + fr) * 64;

  f32x4 acc[8][4] = {};
  f32x4 xv[4][2];

  const int NT = 8;  // K = 512

#define LOADX(t)                                                                     \
  _Pragma("unroll") for (int r4 = 0; r4 < 4; ++r4) {                                 \
    xv[r4][0] = *(const f32x4*)(gX + (size_t)(r4 * 64) * 512 + (t) * 64);            \
    xv[r4][1] = *(const f32x4*)(gX + (size_t)(r4 * 64) * 512 + (t) * 64 + 4);        \
  }

#define STAGE_B1(d, t)                                                               \
  _Pragma("unroll") for (int r4 = 0; r4 < 4; ++r4)                                   \
    gload16(gB + (size_t)(r4 * 64) * 512 + (size_t)(t) * 64,                         \
            lB + (d) * 16384 + r4 * 4096);

#define WRITE_A(d)                                                                   \
  _Pragma("unroll") for (int r4 = 0; r4 < 4; ++r4) {                                 \
    bf16x8 v;                                                                        \
    _Pragma("unroll") for (int i = 0; i < 4; ++i) {                                  \
      v[i] = __builtin_bit_cast(__bf16, f2bf_hw(xv[r4][0][i]));                      \
      v[4 + i] = __builtin_bit_cast(__bf16, f2bf_hw(xv[r4][1][i]));                  \
    }                                                                                \
    *(bf16x8*)(lAsw + (d) * 16384 + r4 * 4096) = v;                                  \
  }

  LOADX(0);
  STAGE_B1(0, 0);
  WRITE_A(0);
  __syncthreads();

  for (int t = 0; t < NT; ++t) {
    const int c = t & 1;
    const int cn = c ^ 1;
    const int tn = (t + 1 < NT) ? t + 1 : NT - 1;

    LOADX(tn);
    STAGE_B1(cn, tn);
    __builtin_amdgcn_sched_barrier(0);

    bf16x8 a0[8], a1[8], b0[4], b1[4];
#pragma unroll
    for (int m = 0; m < 8; ++m) {
      a0[m] = *(const bf16x8*)(fA + c * 16384 + m * 1024 + kp0);
      a1[m] = *(const bf16x8*)(fA + c * 16384 + m * 1024 + kp1);
    }
#pragma unroll
    for (int n = 0; n < 4; ++n) {
      b0[n] = *(const bf16x8*)(fB + c * 16384 + n * 1024 + kp0);
      b1[n] = *(const bf16x8*)(fB + c * 16384 + n * 1024 + kp1);
    }
#pragma unroll
    for (int m = 0; m < 8; ++m)
#pragma unroll
      for (int n = 0; n < 4; ++n)
        acc[m][n] = __builtin_amdgcn_mfma_f32_16x16x32_bf16(a0[m], b0[n], acc[m][n], 0, 0, 0);
#pragma unroll
    for (int m = 0; m < 8; ++m)
#pragma unroll
      for (int n = 0; n < 4; ++n)
        acc[m][n] = __builtin_amdgcn_mfma_f32_16x16x32_bf16(a1[m], b1[n], acc[m][n], 0, 0, 0);

    __builtin_amdgcn_sched_barrier(0);
    WRITE_A(cn);
    __syncthreads();
  }

#pragma unroll
  for (int m = 0; m < 8; ++m) {
    const int r = rowBase + wr * 128 + m * 16 + (lane >> 4) * 4;
#pragma unroll
    for (int n = 0; n < 4; ++n) {
      const int cc = colBase + wc * 64 + n * 16 + (lane & 15);
      ushort4 v;
      v.x = f2bf(acc[m][n][0]);
      v.y = f2bf(acc[m][n][1]);
      v.z = f2bf(acc[m][n][2]);
      v.w = f2bf(acc[m][n][3]);
      *reinterpret_cast<ushort4*>(&Ct[(size_t)cc * M + r]) = v;
    }
  }
#undef LOADX
#undef STAGE_B1
#undef WRITE_A
}

// ---- GEMM2: 128x256 tile, BK=64, single-buffer, 2 blocks/CU (r10, unchanged)
__launch_bounds__(512, 4)
__global__ void gemm2b_k(const u16* __restrict__ A, int lda,
                         const u16* __restrict__ Bt, int ldb,
                         float* __restrict__ C, int ldc,
                         const float* __restrict__ bias, int K,
                         int nMT, int nNT, size_t zBt, size_t zC) {
  __shared__ __align__(16) u16 lds[24576];  // 48 KiB

  const int tid = threadIdx.x;
  const int lane = tid & 63;
  const int wid = tid >> 6;
  const int wr = wid >> 2;
  const int wc = wid & 3;

  const int flat = blockIdx.x;
  const int cpx = (int)gridDim.x >> 3;
  const int wg = (flat & 7) * cpx + (flat >> 3);
  const int m_t = wg % nMT;
  const int rest = wg / nMT;
  const int n_t = rest % nNT;
  const int b = rest / nNT;
  const int rowBase = m_t * 128;
  const int colBase = n_t * 256;
  const u16* Bb = Bt + (size_t)b * zBt;

  const int lr = tid >> 3;
  const int kkl = (tid & 7) * 8;
  const int kswz = kkl ^ ((lr & 7) << 3);
  const u16* gA = A + (size_t)(rowBase + lr) * lda + kswz;
  const u16* gB = Bb + (size_t)(colBase + lr) * ldb + kswz;
  u16* lA = lds + lr * 64 + kkl;
  u16* lB = lds + 8192 + lr * 64 + kkl;

  const int fr = lane & 15;
  const int rswz = (lane & 7) << 3;
  const int kp0 = ((lane >> 4) * 8) ^ rswz;
  const int kp1 = (32 | ((lane >> 4) * 8)) ^ rswz;
  const u16* fA = lds + (wr * 64 + fr) * 64;
  const u16* fB = lds + 8192 + (wc * 64 + fr) * 64;

  f32x4 acc[4][4] = {};
  const int NT = K >> 6;

  for (int t = 0; t < NT; ++t) {
    gload16(gA + (size_t)t * 64, lA);
    gload16(gA + (size_t)64 * lda + (size_t)t * 64, lA + 4096);
#pragma unroll
    for (int r4 = 0; r4 < 4; ++r4)
      gload16(gB + (size_t)(r4 * 64) * ldb + (size_t)t * 64, lB + r4 * 4096);
    __syncthreads();

    bf16x8 a[4], bb[4];
#pragma unroll
    for (int m = 0; m < 4; ++m) a[m] = *(const bf16x8*)(fA + m * 1024 + kp0);
#pragma unroll
    for (int n = 0; n < 4; ++n) bb[n] = *(const bf16x8*)(fB + n * 1024 + kp0);
#pragma unroll
    for (int m = 0; m < 4; ++m)
#pragma unroll
      for (int n = 0; n < 4; ++n)
        acc[m][n] = __builtin_amdgcn_mfma_f32_16x16x32_bf16(a[m], bb[n], acc[m][n], 0, 0, 0);
#pragma unroll
    for (int m = 0; m < 4; ++m) a[m] = *(const bf16x8*)(fA + m * 1024 + kp1);
#pragma unroll
    for (int n = 0; n < 4; ++n) bb[n] = *(const bf16x8*)(fB + n * 1024 + kp1);
#pragma unroll
    for (int m = 0; m < 4; ++m)
#pragma unroll
      for (int n = 0; n < 4; ++n)
        acc[m][n] = __builtin_amdgcn_mfma_f32_16x16x32_bf16(a[m], bb[n], acc[m][n], 0, 0, 0);

    __syncthreads();
  }

  float* Cb = C + (size_t)b * zC;
#pragma unroll
  for (int n = 0; n < 4; ++n) {
    const int cc = colBase + wc * 64 + n * 16 + (lane & 15);
    const float bv = bias[cc];
#pragma unroll
    for (int m = 0; m < 4; ++m) {
      const int r = rowBase + wr * 64 + m * 16 + (lane >> 4) * 4;
#pragma unroll
      for (int j = 0; j < 4; ++j)
        Cb[(size_t)(r + j) * ldc + cc] = acc[m][n][j] + bv;
    }
  }
}

extern "C" void kernel_launch(void* const* d_in, const int* in_sizes, int n_in,
                              void* d_out, int out_size, void* d_ws, size_t ws_size,
                              hipStream_t stream) {
  const int B = 16, N = 2048, FIN = 512, FOUT = 512;
  const float* x    = (const float*)d_in[0];
  const float* adj  = (const float*)d_in[1];
  const float* w    = (const float*)d_in[2];
  const float* bias = (const float*)d_in[3];
  float* out = (float*)d_out;
  char* ws = (char*)d_ws;

  float* dis = (float*)ws;                       // 8 KB
  u16* wt    = (u16*)(ws + 8192);                // 512 KB  W^T [FOUT][FIN]
  u16* nadj  = (u16*)(ws + 532480);              // 8 MB    [N][N]
  u16* st    = (u16*)(ws + 8921088);             // 32 MB   support^T [FOUT][B*N]

  row_deg_k<<<N, 256, 0, stream>>>(adj, dis, N);
  conv_wt_k<<<(FIN * FOUT) / 256, 256, 0, stream>>>(w, wt);
  make_nadj_k<<<(N * N / 4) / 256, 256, 0, stream>>>(adj, dis, nadj, N);

  // GEMM1 (fused x->bf16): st = (x @ wt^T)^T ; grid 128*2 = 256 blocks
  gemm1_xw_k<<<dim3(256), 512, 0, stream>>>(x, wt, st, B * N);

  // GEMM2: out[b] = nadj @ support[b] + bias ; grid 16*2*16 = 512 blocks (2/CU)
  gemm2b_k<<<dim3(512), 512, 0, stream>>>(
      nadj, N, st, B * N, out, FOUT, bias, N, 16, 2,
      (size_t)N, (size_t)N * FOUT);
}